// Round 1
// baseline (276.078 us; speedup 1.0000x reference)
//
#include <hip/hip_runtime.h>
#include <stdint.h>

#define IMG_H 512
#define IMG_W 512
#define NB 16
#define NC 8
#define HW (IMG_H * IMG_W)

// ---------------------------------------------------------------------------
// Kernel 1: boundary bitmask. boundary(p) = any valid 3x3 neighbor differs.
// One block per row (16*512 blocks, 512 threads). __ballot packs 64 pixels.
// ---------------------------------------------------------------------------
__global__ __launch_bounds__(512) void boundary_kernel(const int* __restrict__ tgt,
                                                       uint32_t* __restrict__ mask) {
    int b = blockIdx.x >> 9;
    int y = blockIdx.x & 511;
    int x = threadIdx.x;
    const int* timg = tgt + (size_t)b * HW;
    int t = timg[y * IMG_W + x];
    bool diff = false;
    #pragma unroll
    for (int dy = -1; dy <= 1; dy++) {
        int yy = y + dy;
        if (yy < 0 || yy > IMG_H - 1) continue;
        const int* rowp = timg + yy * IMG_W;
        #pragma unroll
        for (int dx = -1; dx <= 1; dx++) {
            int xx = x + dx;
            if (xx < 0 || xx > IMG_W - 1) continue;
            diff |= (rowp[xx] != t);
        }
    }
    unsigned long long m = __ballot(diff);
    int lane = threadIdx.x & 63;
    size_t widx = (size_t)b * (HW / 32) + y * (IMG_W / 32) + (threadIdx.x >> 5);
    if (lane == 0)
        mask[widx] = (uint32_t)m;
    else if (lane == 32)
        mask[widx] = (uint32_t)(m >> 32);
}

// ---------------------------------------------------------------------------
// Kernel 2: capped Chebyshev distance transform via 15 bit-parallel dilations.
// One block per image; full 512x(16 word) bitmask lives in LDS (32 KB).
// dist(p) = iteration at which p's bit first turns on (1..15), else 0.
// Each thread owns one row; zero-fills its dist row first (ws not re-poisoned
// between replays, so every byte must be written deterministically).
// ---------------------------------------------------------------------------
__global__ __launch_bounds__(512) void dist_kernel(const uint32_t* __restrict__ mask,
                                                   uint8_t* __restrict__ dist) {
    __shared__ uint32_t cur[IMG_H][16];
    int b = blockIdx.x;
    int row = threadIdx.x;
    const uint32_t* m = mask + (size_t)b * (HW / 32);
    uint8_t* db = dist + (size_t)b * HW;

    // zero-fill this row of dist (16B stores)
    uint4* dz = (uint4*)(db + row * IMG_W);
    #pragma unroll
    for (int i = 0; i < IMG_W / 16; i++) dz[i] = make_uint4(0u, 0u, 0u, 0u);

    #pragma unroll
    for (int w = 0; w < 16; w++) cur[row][w] = m[row * 16 + w];
    __syncthreads();

    for (int it = 1; it <= 15; it++) {
        uint32_t oldv[16], outv[16];
        #pragma unroll
        for (int w = 0; w < 16; w++) {
            oldv[w] = cur[row][w];
            uint32_t acc = 0u;
            for (int dr = -1; dr <= 1; dr++) {
                int r = row + dr;
                if (r < 0 || r > IMG_H - 1) continue;
                uint32_t v   = cur[r][w];
                uint32_t lft = (w > 0)  ? cur[r][w - 1] : 0u;
                uint32_t rgt = (w < 15) ? cur[r][w + 1] : 0u;
                acc |= v | (v << 1) | (lft >> 31) | (v >> 1) | (rgt << 31);
            }
            outv[w] = acc;
        }
        __syncthreads();
        #pragma unroll
        for (int w = 0; w < 16; w++) {
            cur[row][w] = outv[w];
            uint32_t nb = outv[w] & ~oldv[w];
            while (nb) {
                int bit = __ffs(nb) - 1;
                nb &= nb - 1;
                db[row * IMG_W + w * 32 + bit] = (uint8_t)it;
            }
        }
        __syncthreads();
    }
}

// ---------------------------------------------------------------------------
// Kernel 3: per-pixel CE (log-softmax over 8 classes) * exp(-dist/5), reduced.
// Each thread: 4 consecutive pixels via float4 loads of the 8 class planes.
// Target-class select via unrolled ?: chain (no runtime array index -> no
// scratch). Wave shuffle reduce -> block -> one double atomicAdd per block.
// ---------------------------------------------------------------------------
__global__ __launch_bounds__(256) void ce_kernel(const float* __restrict__ in,
                                                 const int* __restrict__ tgt,
                                                 const uint8_t* __restrict__ dist,
                                                 double* __restrict__ acc) {
    int gid = blockIdx.x * 256 + threadIdx.x;
    int p4 = gid * 4;
    float partial = 0.0f;
    if (p4 < NB * HW) {
        int b = p4 >> 18;           // / HW
        int r = p4 & (HW - 1);      // % HW
        const float* base = in + (size_t)b * (NC * HW) + r;
        float v[NC][4];
        #pragma unroll
        for (int c = 0; c < NC; c++) {
            float4 q = *(const float4*)(base + (size_t)c * HW);
            v[c][0] = q.x; v[c][1] = q.y; v[c][2] = q.z; v[c][3] = q.w;
        }
        int4 t4 = *(const int4*)(tgt + p4);
        int tv[4] = {t4.x, t4.y, t4.z, t4.w};
        uint32_t d4 = *(const uint32_t*)(dist + p4);
        #pragma unroll
        for (int j = 0; j < 4; j++) {
            float mx = v[0][j];
            #pragma unroll
            for (int c = 1; c < NC; c++) mx = fmaxf(mx, v[c][j]);
            float s = 0.0f;
            #pragma unroll
            for (int c = 0; c < NC; c++) s += __expf(v[c][j] - mx);
            float lse = mx + __logf(s);
            int t = tv[j];
            float lt = v[0][j];
            #pragma unroll
            for (int c = 1; c < NC; c++) lt = (t == c) ? v[c][j] : lt;
            float ce = lse - lt;
            float d = (float)((d4 >> (8 * j)) & 0xffu);
            partial += __expf(d * -0.2f) * ce;
        }
    }
    // wave64 reduce
    #pragma unroll
    for (int off = 32; off > 0; off >>= 1) partial += __shfl_down(partial, off);
    __shared__ float wsums[4];
    int lane = threadIdx.x & 63;
    int wid = threadIdx.x >> 6;
    if (lane == 0) wsums[wid] = partial;
    __syncthreads();
    if (threadIdx.x == 0) {
        float s = wsums[0] + wsums[1] + wsums[2] + wsums[3];
        atomicAdd(acc, (double)s);
    }
}

__global__ void finalize_kernel(const double* __restrict__ acc, float* __restrict__ out) {
    out[0] = (float)(acc[0] * (1.0 / (double)((size_t)NB * HW)));
}

extern "C" void kernel_launch(void* const* d_in, const int* in_sizes, int n_in,
                              void* d_out, int out_size, void* d_ws, size_t ws_size,
                              hipStream_t stream) {
    const float* in  = (const float*)d_in[0];
    const int*   tgt = (const int*)d_in[1];
    float* out = (float*)d_out;

    char* ws = (char*)d_ws;
    double*   acc  = (double*)ws;                                   // 8 B
    uint32_t* mask = (uint32_t*)(ws + 256);                         // 512 KB
    uint8_t*  dist = (uint8_t*)(ws + 256 + (size_t)NB * (HW / 32) * 4); // 4 MB

    hipMemsetAsync(acc, 0, sizeof(double), stream);
    boundary_kernel<<<NB * IMG_H, IMG_W, 0, stream>>>(tgt, mask);
    dist_kernel<<<NB, IMG_H, 0, stream>>>(mask, dist);
    ce_kernel<<<(NB * HW) / 1024, 256, 0, stream>>>(in, tgt, dist, acc);
    finalize_kernel<<<1, 1, 0, stream>>>(acc, out);
}

// Round 2
// 104.154 us; speedup vs baseline: 2.6507x; 2.6507x over previous
//
#include <hip/hip_runtime.h>
#include <stdint.h>

#define IMG_H 512
#define IMG_W 512
#define NB 16
#define NC 8
#define HW (IMG_H * IMG_W)

#define TILE 64
#define HALO 15
#define RROWS (TILE + 2 * HALO)   // 94

// ---------------------------------------------------------------------------
// Kernel 1: boundary bitmask. boundary(p) = any valid 3x3 neighbor differs.
// One block per row (16*512 blocks, 512 threads). __ballot packs 64 pixels.
// ---------------------------------------------------------------------------
__global__ __launch_bounds__(512) void boundary_kernel(const int* __restrict__ tgt,
                                                       uint32_t* __restrict__ mask) {
    int b = blockIdx.x >> 9;
    int y = blockIdx.x & 511;
    int x = threadIdx.x;
    const int* timg = tgt + (size_t)b * HW;
    int t = timg[y * IMG_W + x];
    bool diff = false;
    #pragma unroll
    for (int dy = -1; dy <= 1; dy++) {
        int yy = y + dy;
        if (yy < 0 || yy > IMG_H - 1) continue;
        const int* rowp = timg + yy * IMG_W;
        #pragma unroll
        for (int dx = -1; dx <= 1; dx++) {
            int xx = x + dx;
            if (xx < 0 || xx > IMG_W - 1) continue;
            diff |= (rowp[xx] != t);
        }
    }
    unsigned long long m = __ballot(diff);
    int lane = threadIdx.x & 63;
    size_t widx = (size_t)b * (HW / 32) + y * (IMG_W / 32) + (threadIdx.x >> 5);
    if (lane == 0)
        mask[widx] = (uint32_t)m;
    else if (lane == 32)
        mask[widx] = (uint32_t)(m >> 32);
}

// ---------------------------------------------------------------------------
// Kernel 2: capped Chebyshev distance transform, TILED.
// The 15-iteration dilation has dependency radius 15, so each 64x64 output
// tile depends only on a 94x94 bitmask region (94 rows x 4 words with the
// 15-bit column halo inside words [wx-1 .. wx+2]). One block per tile:
// 16 images x 64 tiles = 1024 blocks, 128 threads (one row each).
// After 15 iters the edge-wrongness wavefront (from treating outside-region
// as 0) has advanced only 15 rows/bits inward -> the central 64x64 is exact.
// LDS row stride padded to 5 words (odd) -> conflict-free neighbor reads.
// dist staged in a 64x64 LDS tile (init 0) and written out coalesced, which
// also serves as the deterministic zero-fill of the dist buffer.
// ---------------------------------------------------------------------------
__global__ __launch_bounds__(128) void dist_kernel(const uint32_t* __restrict__ mask,
                                                   uint8_t* __restrict__ dist) {
    __shared__ uint32_t cur[RROWS][5];
    __shared__ uint8_t dtile[TILE][TILE];
    int b   = blockIdx.x >> 6;
    int tid = blockIdx.x & 63;
    int ty = tid >> 3, tx = tid & 7;
    int ry = ty * TILE;          // tile top row in image
    int wx = tx * 2;             // tile leftmost mask word
    const uint32_t* m = mask + (size_t)b * (HW / 32);
    uint8_t* db = dist + (size_t)b * HW;
    int t = threadIdx.x;

    // zero the LDS dist tile (4096 B / 128 thr = 32 B each)
    {
        uint4* dz = (uint4*)dtile;
        dz[t * 2]     = make_uint4(0u, 0u, 0u, 0u);
        dz[t * 2 + 1] = make_uint4(0u, 0u, 0u, 0u);
    }
    // load the 94x4-word region (clamp to 0 outside the image)
    if (t < RROWS) {
        int g = ry - HALO + t;
        #pragma unroll
        for (int w = 0; w < 4; w++) {
            int gw = wx - 1 + w;
            uint32_t v = 0u;
            if (g >= 0 && g < IMG_H && gw >= 0 && gw < 16) v = m[g * 16 + gw];
            cur[t][w] = v;
        }
    }
    __syncthreads();

    bool inrow = (t >= HALO && t < HALO + TILE);
    for (int it = 1; it <= 15; it++) {
        uint32_t nw[4] = {0u, 0u, 0u, 0u};
        uint32_t old1 = 0u, old2 = 0u;
        if (t < RROWS) {
            old1 = cur[t][1];
            old2 = cur[t][2];
            #pragma unroll
            for (int w = 0; w < 4; w++) {
                uint32_t acc = 0u;
                #pragma unroll
                for (int dr = -1; dr <= 1; dr++) {
                    int r = t + dr;
                    if (r < 0 || r > RROWS - 1) continue;
                    uint32_t v   = cur[r][w];
                    uint32_t lft = (w > 0) ? cur[r][w - 1] : 0u;
                    uint32_t rgt = (w < 3) ? cur[r][w + 1] : 0u;
                    acc |= v | (v << 1) | (lft >> 31) | (v >> 1) | (rgt << 31);
                }
                nw[w] = acc;
            }
        }
        __syncthreads();
        if (t < RROWS) {
            #pragma unroll
            for (int w = 0; w < 4; w++) cur[t][w] = nw[w];
            if (inrow) {
                int lrow = t - HALO;
                uint32_t nb = nw[1] & ~old1;
                while (nb) { int bit = __ffs(nb) - 1; nb &= nb - 1; dtile[lrow][bit] = (uint8_t)it; }
                nb = nw[2] & ~old2;
                while (nb) { int bit = __ffs(nb) - 1; nb &= nb - 1; dtile[lrow][32 + bit] = (uint8_t)it; }
            }
        }
        __syncthreads();
    }

    // write the 64x64 tile: 256 uint4 stores, 2 per thread, coalesced
    #pragma unroll
    for (int k = 0; k < 2; k++) {
        int f = t + 128 * k;
        int row = f >> 2, q = f & 3;
        *(uint4*)(db + (size_t)(ry + row) * IMG_W + tx * TILE + q * 16) =
            ((const uint4*)dtile)[f];
    }
}

// ---------------------------------------------------------------------------
// Kernel 3: per-pixel CE (log-softmax over 8 classes) * exp(-dist/5), reduced.
// ---------------------------------------------------------------------------
__global__ __launch_bounds__(256) void ce_kernel(const float* __restrict__ in,
                                                 const int* __restrict__ tgt,
                                                 const uint8_t* __restrict__ dist,
                                                 double* __restrict__ acc) {
    int gid = blockIdx.x * 256 + threadIdx.x;
    int p4 = gid * 4;
    float partial = 0.0f;
    if (p4 < NB * HW) {
        int b = p4 >> 18;           // / HW
        int r = p4 & (HW - 1);      // % HW
        const float* base = in + (size_t)b * (NC * HW) + r;
        float v[NC][4];
        #pragma unroll
        for (int c = 0; c < NC; c++) {
            float4 q = *(const float4*)(base + (size_t)c * HW);
            v[c][0] = q.x; v[c][1] = q.y; v[c][2] = q.z; v[c][3] = q.w;
        }
        int4 t4 = *(const int4*)(tgt + p4);
        int tv[4] = {t4.x, t4.y, t4.z, t4.w};
        uint32_t d4 = *(const uint32_t*)(dist + p4);
        #pragma unroll
        for (int j = 0; j < 4; j++) {
            float mx = v[0][j];
            #pragma unroll
            for (int c = 1; c < NC; c++) mx = fmaxf(mx, v[c][j]);
            float s = 0.0f;
            #pragma unroll
            for (int c = 0; c < NC; c++) s += __expf(v[c][j] - mx);
            float lse = mx + __logf(s);
            int t = tv[j];
            float lt = v[0][j];
            #pragma unroll
            for (int c = 1; c < NC; c++) lt = (t == c) ? v[c][j] : lt;
            float ce = lse - lt;
            float d = (float)((d4 >> (8 * j)) & 0xffu);
            partial += __expf(d * -0.2f) * ce;
        }
    }
    #pragma unroll
    for (int off = 32; off > 0; off >>= 1) partial += __shfl_down(partial, off);
    __shared__ float wsums[4];
    int lane = threadIdx.x & 63;
    int wid = threadIdx.x >> 6;
    if (lane == 0) wsums[wid] = partial;
    __syncthreads();
    if (threadIdx.x == 0) {
        float s = wsums[0] + wsums[1] + wsums[2] + wsums[3];
        atomicAdd(acc, (double)s);
    }
}

__global__ void finalize_kernel(const double* __restrict__ acc, float* __restrict__ out) {
    out[0] = (float)(acc[0] * (1.0 / (double)((size_t)NB * HW)));
}

extern "C" void kernel_launch(void* const* d_in, const int* in_sizes, int n_in,
                              void* d_out, int out_size, void* d_ws, size_t ws_size,
                              hipStream_t stream) {
    const float* in  = (const float*)d_in[0];
    const int*   tgt = (const int*)d_in[1];
    float* out = (float*)d_out;

    char* ws = (char*)d_ws;
    double*   acc  = (double*)ws;                                        // 8 B
    uint32_t* mask = (uint32_t*)(ws + 256);                              // 512 KB
    uint8_t*  dist = (uint8_t*)(ws + 256 + (size_t)NB * (HW / 32) * 4);  // 4 MB

    hipMemsetAsync(acc, 0, sizeof(double), stream);
    boundary_kernel<<<NB * IMG_H, IMG_W, 0, stream>>>(tgt, mask);
    dist_kernel<<<NB * 64, 128, 0, stream>>>(mask, dist);
    ce_kernel<<<(NB * HW) / 1024, 256, 0, stream>>>(in, tgt, dist, acc);
    finalize_kernel<<<1, 1, 0, stream>>>(acc, out);
}

// Round 3
// 99.126 us; speedup vs baseline: 2.7851x; 1.0507x over previous
//
#include <hip/hip_runtime.h>
#include <stdint.h>

#define IMG_H 512
#define IMG_W 512
#define NB 16
#define NC 8
#define HW (IMG_H * IMG_W)

#define TILE 64
#define HALO 15
#define RROWS (TILE + 2 * HALO)   // 94

// ---------------------------------------------------------------------------
// Kernel 1: boundary bitmask. boundary(p) = any valid 3x3 neighbor differs.
// One block per row (16*512 blocks, 512 threads). __ballot packs 64 pixels.
// Block 0 / thread 0 also zeroes the double accumulator (replaces the
// pathological 8-byte hipMemsetAsync fill kernel: 75 us/replay in-graph).
// ---------------------------------------------------------------------------
__global__ __launch_bounds__(512) void boundary_kernel(const int* __restrict__ tgt,
                                                       uint32_t* __restrict__ mask,
                                                       double* __restrict__ acc) {
    if (blockIdx.x == 0 && threadIdx.x == 0) acc[0] = 0.0;
    int b = blockIdx.x >> 9;
    int y = blockIdx.x & 511;
    int x = threadIdx.x;
    const int* timg = tgt + (size_t)b * HW;
    int t = timg[y * IMG_W + x];
    bool diff = false;
    #pragma unroll
    for (int dy = -1; dy <= 1; dy++) {
        int yy = y + dy;
        if (yy < 0 || yy > IMG_H - 1) continue;
        const int* rowp = timg + yy * IMG_W;
        #pragma unroll
        for (int dx = -1; dx <= 1; dx++) {
            int xx = x + dx;
            if (xx < 0 || xx > IMG_W - 1) continue;
            diff |= (rowp[xx] != t);
        }
    }
    unsigned long long m = __ballot(diff);
    int lane = threadIdx.x & 63;
    size_t widx = (size_t)b * (HW / 32) + y * (IMG_W / 32) + (threadIdx.x >> 5);
    if (lane == 0)
        mask[widx] = (uint32_t)m;
    else if (lane == 32)
        mask[widx] = (uint32_t)(m >> 32);
}

// ---------------------------------------------------------------------------
// Kernel 2: capped Chebyshev distance transform, TILED.
// 15-iter dilation has dependency radius 15 -> each 64x64 output tile depends
// only on a 94x94 bitmask region. 16 images x 64 tiles = 1024 blocks.
// LDS row stride 5 words (odd) -> conflict-free neighbor reads.
// dist staged in LDS (init 0) and written coalesced (doubles as zero-fill).
// ---------------------------------------------------------------------------
__global__ __launch_bounds__(128) void dist_kernel(const uint32_t* __restrict__ mask,
                                                   uint8_t* __restrict__ dist) {
    __shared__ uint32_t cur[RROWS][5];
    __shared__ uint8_t dtile[TILE][TILE];
    int b   = blockIdx.x >> 6;
    int tid = blockIdx.x & 63;
    int ty = tid >> 3, tx = tid & 7;
    int ry = ty * TILE;          // tile top row in image
    int wx = tx * 2;             // tile leftmost mask word
    const uint32_t* m = mask + (size_t)b * (HW / 32);
    uint8_t* db = dist + (size_t)b * HW;
    int t = threadIdx.x;

    {
        uint4* dz = (uint4*)dtile;
        dz[t * 2]     = make_uint4(0u, 0u, 0u, 0u);
        dz[t * 2 + 1] = make_uint4(0u, 0u, 0u, 0u);
    }
    if (t < RROWS) {
        int g = ry - HALO + t;
        #pragma unroll
        for (int w = 0; w < 4; w++) {
            int gw = wx - 1 + w;
            uint32_t v = 0u;
            if (g >= 0 && g < IMG_H && gw >= 0 && gw < 16) v = m[g * 16 + gw];
            cur[t][w] = v;
        }
    }
    __syncthreads();

    bool inrow = (t >= HALO && t < HALO + TILE);
    for (int it = 1; it <= 15; it++) {
        uint32_t nw[4] = {0u, 0u, 0u, 0u};
        uint32_t old1 = 0u, old2 = 0u;
        if (t < RROWS) {
            old1 = cur[t][1];
            old2 = cur[t][2];
            #pragma unroll
            for (int w = 0; w < 4; w++) {
                uint32_t acc = 0u;
                #pragma unroll
                for (int dr = -1; dr <= 1; dr++) {
                    int r = t + dr;
                    if (r < 0 || r > RROWS - 1) continue;
                    uint32_t v   = cur[r][w];
                    uint32_t lft = (w > 0) ? cur[r][w - 1] : 0u;
                    uint32_t rgt = (w < 3) ? cur[r][w + 1] : 0u;
                    acc |= v | (v << 1) | (lft >> 31) | (v >> 1) | (rgt << 31);
                }
                nw[w] = acc;
            }
        }
        __syncthreads();
        if (t < RROWS) {
            #pragma unroll
            for (int w = 0; w < 4; w++) cur[t][w] = nw[w];
            if (inrow) {
                int lrow = t - HALO;
                uint32_t nb = nw[1] & ~old1;
                while (nb) { int bit = __ffs(nb) - 1; nb &= nb - 1; dtile[lrow][bit] = (uint8_t)it; }
                nb = nw[2] & ~old2;
                while (nb) { int bit = __ffs(nb) - 1; nb &= nb - 1; dtile[lrow][32 + bit] = (uint8_t)it; }
            }
        }
        __syncthreads();
    }

    #pragma unroll
    for (int k = 0; k < 2; k++) {
        int f = t + 128 * k;
        int row = f >> 2, q = f & 3;
        *(uint4*)(db + (size_t)(ry + row) * IMG_W + tx * TILE + q * 16) =
            ((const uint4*)dtile)[f];
    }
}

// ---------------------------------------------------------------------------
// Kernel 3: per-pixel CE (log-softmax over 8 classes) * exp(-dist/5), reduced.
// ---------------------------------------------------------------------------
__global__ __launch_bounds__(256) void ce_kernel(const float* __restrict__ in,
                                                 const int* __restrict__ tgt,
                                                 const uint8_t* __restrict__ dist,
                                                 double* __restrict__ acc) {
    int gid = blockIdx.x * 256 + threadIdx.x;
    int p4 = gid * 4;
    float partial = 0.0f;
    if (p4 < NB * HW) {
        int b = p4 >> 18;           // / HW
        int r = p4 & (HW - 1);      // % HW
        const float* base = in + (size_t)b * (NC * HW) + r;
        float v[NC][4];
        #pragma unroll
        for (int c = 0; c < NC; c++) {
            float4 q = *(const float4*)(base + (size_t)c * HW);
            v[c][0] = q.x; v[c][1] = q.y; v[c][2] = q.z; v[c][3] = q.w;
        }
        int4 t4 = *(const int4*)(tgt + p4);
        int tv[4] = {t4.x, t4.y, t4.z, t4.w};
        uint32_t d4 = *(const uint32_t*)(dist + p4);
        #pragma unroll
        for (int j = 0; j < 4; j++) {
            float mx = v[0][j];
            #pragma unroll
            for (int c = 1; c < NC; c++) mx = fmaxf(mx, v[c][j]);
            float s = 0.0f;
            #pragma unroll
            for (int c = 0; c < NC; c++) s += __expf(v[c][j] - mx);
            float lse = mx + __logf(s);
            int t = tv[j];
            float lt = v[0][j];
            #pragma unroll
            for (int c = 1; c < NC; c++) lt = (t == c) ? v[c][j] : lt;
            float ce = lse - lt;
            float d = (float)((d4 >> (8 * j)) & 0xffu);
            partial += __expf(d * -0.2f) * ce;
        }
    }
    #pragma unroll
    for (int off = 32; off > 0; off >>= 1) partial += __shfl_down(partial, off);
    __shared__ float wsums[4];
    int lane = threadIdx.x & 63;
    int wid = threadIdx.x >> 6;
    if (lane == 0) wsums[wid] = partial;
    __syncthreads();
    if (threadIdx.x == 0) {
        float s = wsums[0] + wsums[1] + wsums[2] + wsums[3];
        atomicAdd(acc, (double)s);
    }
}

__global__ void finalize_kernel(const double* __restrict__ acc, float* __restrict__ out) {
    out[0] = (float)(acc[0] * (1.0 / (double)((size_t)NB * HW)));
}

extern "C" void kernel_launch(void* const* d_in, const int* in_sizes, int n_in,
                              void* d_out, int out_size, void* d_ws, size_t ws_size,
                              hipStream_t stream) {
    const float* in  = (const float*)d_in[0];
    const int*   tgt = (const int*)d_in[1];
    float* out = (float*)d_out;

    char* ws = (char*)d_ws;
    double*   acc  = (double*)ws;                                        // 8 B
    uint32_t* mask = (uint32_t*)(ws + 256);                              // 512 KB
    uint8_t*  dist = (uint8_t*)(ws + 256 + (size_t)NB * (HW / 32) * 4);  // 4 MB

    boundary_kernel<<<NB * IMG_H, IMG_W, 0, stream>>>(tgt, mask, acc);
    dist_kernel<<<NB * 64, 128, 0, stream>>>(mask, dist);
    ce_kernel<<<(NB * HW) / 1024, 256, 0, stream>>>(in, tgt, dist, acc);
    finalize_kernel<<<1, 1, 0, stream>>>(acc, out);
}

// Round 4
// 67.874 us; speedup vs baseline: 4.0675x; 1.4604x over previous
//
#include <hip/hip_runtime.h>
#include <stdint.h>

#define IMG_H 512
#define IMG_W 512
#define NB 16
#define NC 8
#define HW (IMG_H * IMG_W)

#define TILE 64
#define HALO 15
#define RROWS (TILE + 2 * HALO)   // 94

#define CE_BLOCKS ((NB * HW) / 1024)   // 4096 blocks, 256 thr, 4 px/thr

// ---------------------------------------------------------------------------
// Kernel 1: boundary bitmask. boundary(p) = any valid 3x3 neighbor differs.
// One block per row (16*512 blocks, 512 threads). __ballot packs 64 pixels.
// ---------------------------------------------------------------------------
__global__ __launch_bounds__(512) void boundary_kernel(const int* __restrict__ tgt,
                                                       uint32_t* __restrict__ mask) {
    int b = blockIdx.x >> 9;
    int y = blockIdx.x & 511;
    int x = threadIdx.x;
    const int* timg = tgt + (size_t)b * HW;
    int t = timg[y * IMG_W + x];
    bool diff = false;
    #pragma unroll
    for (int dy = -1; dy <= 1; dy++) {
        int yy = y + dy;
        if (yy < 0 || yy > IMG_H - 1) continue;
        const int* rowp = timg + yy * IMG_W;
        #pragma unroll
        for (int dx = -1; dx <= 1; dx++) {
            int xx = x + dx;
            if (xx < 0 || xx > IMG_W - 1) continue;
            diff |= (rowp[xx] != t);
        }
    }
    unsigned long long m = __ballot(diff);
    int lane = threadIdx.x & 63;
    size_t widx = (size_t)b * (HW / 32) + y * (IMG_W / 32) + (threadIdx.x >> 5);
    if (lane == 0)
        mask[widx] = (uint32_t)m;
    else if (lane == 32)
        mask[widx] = (uint32_t)(m >> 32);
}

// ---------------------------------------------------------------------------
// Kernel 2: capped Chebyshev distance transform, TILED (radius-15 dependency
// -> 64x64 tile needs only a 94x94 bitmask region). 1024 blocks, 128 thr.
// LDS row stride 5 words (odd) -> conflict-free. dist staged in LDS (init 0)
// and written coalesced (doubles as the deterministic zero-fill).
// ---------------------------------------------------------------------------
__global__ __launch_bounds__(128) void dist_kernel(const uint32_t* __restrict__ mask,
                                                   uint8_t* __restrict__ dist) {
    __shared__ uint32_t cur[RROWS][5];
    __shared__ uint8_t dtile[TILE][TILE];
    int b   = blockIdx.x >> 6;
    int tid = blockIdx.x & 63;
    int ty = tid >> 3, tx = tid & 7;
    int ry = ty * TILE;
    int wx = tx * 2;
    const uint32_t* m = mask + (size_t)b * (HW / 32);
    uint8_t* db = dist + (size_t)b * HW;
    int t = threadIdx.x;

    {
        uint4* dz = (uint4*)dtile;
        dz[t * 2]     = make_uint4(0u, 0u, 0u, 0u);
        dz[t * 2 + 1] = make_uint4(0u, 0u, 0u, 0u);
    }
    if (t < RROWS) {
        int g = ry - HALO + t;
        #pragma unroll
        for (int w = 0; w < 4; w++) {
            int gw = wx - 1 + w;
            uint32_t v = 0u;
            if (g >= 0 && g < IMG_H && gw >= 0 && gw < 16) v = m[g * 16 + gw];
            cur[t][w] = v;
        }
    }
    __syncthreads();

    bool inrow = (t >= HALO && t < HALO + TILE);
    for (int it = 1; it <= 15; it++) {
        uint32_t nw[4] = {0u, 0u, 0u, 0u};
        uint32_t old1 = 0u, old2 = 0u;
        if (t < RROWS) {
            old1 = cur[t][1];
            old2 = cur[t][2];
            #pragma unroll
            for (int w = 0; w < 4; w++) {
                uint32_t acc = 0u;
                #pragma unroll
                for (int dr = -1; dr <= 1; dr++) {
                    int r = t + dr;
                    if (r < 0 || r > RROWS - 1) continue;
                    uint32_t v   = cur[r][w];
                    uint32_t lft = (w > 0) ? cur[r][w - 1] : 0u;
                    uint32_t rgt = (w < 3) ? cur[r][w + 1] : 0u;
                    acc |= v | (v << 1) | (lft >> 31) | (v >> 1) | (rgt << 31);
                }
                nw[w] = acc;
            }
        }
        __syncthreads();
        if (t < RROWS) {
            #pragma unroll
            for (int w = 0; w < 4; w++) cur[t][w] = nw[w];
            if (inrow) {
                int lrow = t - HALO;
                uint32_t nb = nw[1] & ~old1;
                while (nb) { int bit = __ffs(nb) - 1; nb &= nb - 1; dtile[lrow][bit] = (uint8_t)it; }
                nb = nw[2] & ~old2;
                while (nb) { int bit = __ffs(nb) - 1; nb &= nb - 1; dtile[lrow][32 + bit] = (uint8_t)it; }
            }
        }
        __syncthreads();
    }

    #pragma unroll
    for (int k = 0; k < 2; k++) {
        int f = t + 128 * k;
        int row = f >> 2, q = f & 3;
        *(uint4*)(db + (size_t)(ry + row) * IMG_W + tx * TILE + q * 16) =
            ((const uint4*)dtile)[f];
    }
}

// ---------------------------------------------------------------------------
// Kernel 3: per-pixel CE (log-softmax over 8 classes) * exp(-dist/5).
// NO atomics: each block writes one float partial (4096 same-address double
// atomicAdds were serializing at ~60 us of tail). Wave shuffle -> LDS ->
// one coalesced store per block.
// ---------------------------------------------------------------------------
__global__ __launch_bounds__(256) void ce_kernel(const float* __restrict__ in,
                                                 const int* __restrict__ tgt,
                                                 const uint8_t* __restrict__ dist,
                                                 float* __restrict__ partials) {
    int gid = blockIdx.x * 256 + threadIdx.x;
    int p4 = gid * 4;
    float partial = 0.0f;
    {
        int b = p4 >> 18;           // / HW
        int r = p4 & (HW - 1);      // % HW
        const float* base = in + (size_t)b * (NC * HW) + r;
        float v[NC][4];
        #pragma unroll
        for (int c = 0; c < NC; c++) {
            float4 q = *(const float4*)(base + (size_t)c * HW);
            v[c][0] = q.x; v[c][1] = q.y; v[c][2] = q.z; v[c][3] = q.w;
        }
        int4 t4 = *(const int4*)(tgt + p4);
        int tv[4] = {t4.x, t4.y, t4.z, t4.w};
        uint32_t d4 = *(const uint32_t*)(dist + p4);
        #pragma unroll
        for (int j = 0; j < 4; j++) {
            float mx = v[0][j];
            #pragma unroll
            for (int c = 1; c < NC; c++) mx = fmaxf(mx, v[c][j]);
            float s = 0.0f;
            #pragma unroll
            for (int c = 0; c < NC; c++) s += __expf(v[c][j] - mx);
            float lse = mx + __logf(s);
            int t = tv[j];
            float lt = v[0][j];
            #pragma unroll
            for (int c = 1; c < NC; c++) lt = (t == c) ? v[c][j] : lt;
            float ce = lse - lt;
            float d = (float)((d4 >> (8 * j)) & 0xffu);
            partial += __expf(d * -0.2f) * ce;
        }
    }
    #pragma unroll
    for (int off = 32; off > 0; off >>= 1) partial += __shfl_down(partial, off);
    __shared__ float wsums[4];
    int lane = threadIdx.x & 63;
    int wid = threadIdx.x >> 6;
    if (lane == 0) wsums[wid] = partial;
    __syncthreads();
    if (threadIdx.x == 0)
        partials[blockIdx.x] = wsums[0] + wsums[1] + wsums[2] + wsums[3];
}

// ---------------------------------------------------------------------------
// Kernel 4: deterministic tree-reduce of 4096 partials -> mean. One block.
// ---------------------------------------------------------------------------
__global__ __launch_bounds__(256) void reduce_kernel(const float* __restrict__ partials,
                                                     float* __restrict__ out) {
    double s = 0.0;
    #pragma unroll
    for (int i = 0; i < CE_BLOCKS / 256; i++)
        s += (double)partials[threadIdx.x + 256 * i];
    #pragma unroll
    for (int off = 32; off > 0; off >>= 1) s += __shfl_down(s, off);
    __shared__ double wsums[4];
    int lane = threadIdx.x & 63;
    int wid = threadIdx.x >> 6;
    if (lane == 0) wsums[wid] = s;
    __syncthreads();
    if (threadIdx.x == 0) {
        double tot = wsums[0] + wsums[1] + wsums[2] + wsums[3];
        out[0] = (float)(tot * (1.0 / (double)((size_t)NB * HW)));
    }
}

extern "C" void kernel_launch(void* const* d_in, const int* in_sizes, int n_in,
                              void* d_out, int out_size, void* d_ws, size_t ws_size,
                              hipStream_t stream) {
    const float* in  = (const float*)d_in[0];
    const int*   tgt = (const int*)d_in[1];
    float* out = (float*)d_out;

    char* ws = (char*)d_ws;
    uint32_t* mask     = (uint32_t*)(ws + 256);                              // 512 KB
    uint8_t*  dist     = (uint8_t*)(ws + 256 + (size_t)NB * (HW / 32) * 4);  // 4 MB
    float*    partials = (float*)(ws + 256 + (size_t)NB * (HW / 32) * 4 + (size_t)NB * HW); // 16 KB

    boundary_kernel<<<NB * IMG_H, IMG_W, 0, stream>>>(tgt, mask);
    dist_kernel<<<NB * 64, 128, 0, stream>>>(mask, dist);
    ce_kernel<<<CE_BLOCKS, 256, 0, stream>>>(in, tgt, dist, partials);
    reduce_kernel<<<1, 256, 0, stream>>>(partials, out);
}

// Round 5
// 65.146 us; speedup vs baseline: 4.2378x; 1.0419x over previous
//
#include <hip/hip_runtime.h>
#include <stdint.h>

#define IMG_H 512
#define IMG_W 512
#define NB 16
#define NC 8
#define HW (IMG_H * IMG_W)

#define TILE 64
#define HALO 15
#define RROWS (TILE + 2 * HALO)   // 94
#define NTASK (RROWS * 4)         // 376 (row, word) tasks
#define NBLK (NB * 64)            // 1024 tile blocks

// ---------------------------------------------------------------------------
// Kernel 1: boundary bitmask. boundary(p) = any valid 3x3 neighbor differs.
// One block per row (16*512 blocks, 512 threads). __ballot packs 64 pixels.
// ---------------------------------------------------------------------------
__global__ __launch_bounds__(512) void boundary_kernel(const int* __restrict__ tgt,
                                                       uint32_t* __restrict__ mask) {
    int b = blockIdx.x >> 9;
    int y = blockIdx.x & 511;
    int x = threadIdx.x;
    const int* timg = tgt + (size_t)b * HW;
    int t = timg[y * IMG_W + x];
    bool diff = false;
    #pragma unroll
    for (int dy = -1; dy <= 1; dy++) {
        int yy = y + dy;
        if (yy < 0 || yy > IMG_H - 1) continue;
        const int* rowp = timg + yy * IMG_W;
        #pragma unroll
        for (int dx = -1; dx <= 1; dx++) {
            int xx = x + dx;
            if (xx < 0 || xx > IMG_W - 1) continue;
            diff |= (rowp[xx] != t);
        }
    }
    unsigned long long m = __ballot(diff);
    int lane = threadIdx.x & 63;
    size_t widx = (size_t)b * (HW / 32) + y * (IMG_W / 32) + (threadIdx.x >> 5);
    if (lane == 0)
        mask[widx] = (uint32_t)m;
    else if (lane == 32)
        mask[widx] = (uint32_t)(m >> 32);
}

// ---------------------------------------------------------------------------
// Kernel 2 (FUSED dist + ce): one block per 64x64 tile (1024 blocks, 256 thr).
// Phase A: load 94x4-word mask halo into LDS, 15 bit-parallel dilations ->
//          dtile[64][64] (uint8 Chebyshev dist capped at 15; never-reached=0).
//          Radius-15 dependency proves the tile is exact (verified R1-R4).
// Phase B: stream the tile's logits (8 planes) + targets, CE * exp(-dist/5)
//          with dist straight from LDS. No dist/HBM round-trip.
// Block partial -> partials[blockIdx.x] (atomic-free, verified R4).
// ---------------------------------------------------------------------------
__global__ __launch_bounds__(256) void distce_kernel(const float* __restrict__ in,
                                                     const int* __restrict__ tgt,
                                                     const uint32_t* __restrict__ mask,
                                                     float* __restrict__ partials) {
    __shared__ uint32_t cur[RROWS][5];   // stride 5 words: conflict-light
    __shared__ uint8_t dtile[TILE][TILE];
    int b   = blockIdx.x >> 6;
    int tid = blockIdx.x & 63;
    int ty = tid >> 3, tx = tid & 7;
    int ry = ty * TILE;                  // tile top row in image
    int wx = tx * 2;                     // tile leftmost mask word
    const uint32_t* m = mask + (size_t)b * (HW / 32);
    int t = threadIdx.x;

    // zero dist tile: 4096 B / 256 thr = one uint4 each
    ((uint4*)dtile)[t] = make_uint4(0u, 0u, 0u, 0u);

    // load mask halo region: 376 (row,word) tasks over 256 threads
    #pragma unroll
    for (int k = 0; k < 2; k++) {
        int task = t + 256 * k;
        if (task < NTASK) {
            int r = task >> 2, w = task & 3;
            int g  = ry - HALO + r;
            int gw = wx - 1 + w;
            uint32_t v = 0u;
            if ((unsigned)g < IMG_H && (unsigned)gw < 16u) v = m[g * 16 + gw];
            cur[r][w] = v;
        }
    }
    __syncthreads();

    // 15 dilation iterations; each thread owns up to 2 (row,word) tasks
    int r0 = t >> 2, w0 = t & 3;              // task0: always valid
    int r1 = (t + 256) >> 2, w1 = t & 3;      // task1: valid for t < 120
    bool has1 = (t + 256) < NTASK;
    for (int it = 1; it <= 15; it++) {
        uint32_t nw0 = 0u, nw1 = 0u, old0, old1 = 0u;
        old0 = cur[r0][w0];
        #pragma unroll
        for (int dr = -1; dr <= 1; dr++) {
            int rr = r0 + dr;
            if ((unsigned)rr >= (unsigned)RROWS) continue;
            uint32_t v   = cur[rr][w0];
            uint32_t lft = (w0 > 0) ? cur[rr][w0 - 1] : 0u;
            uint32_t rgt = (w0 < 3) ? cur[rr][w0 + 1] : 0u;
            nw0 |= v | (v << 1) | (v >> 1) | (lft >> 31) | (rgt << 31);
        }
        if (has1) {
            old1 = cur[r1][w1];
            #pragma unroll
            for (int dr = -1; dr <= 1; dr++) {
                int rr = r1 + dr;
                if ((unsigned)rr >= (unsigned)RROWS) continue;
                uint32_t v   = cur[rr][w1];
                uint32_t lft = (w1 > 0) ? cur[rr][w1 - 1] : 0u;
                uint32_t rgt = (w1 < 3) ? cur[rr][w1 + 1] : 0u;
                nw1 |= v | (v << 1) | (v >> 1) | (lft >> 31) | (rgt << 31);
            }
        }
        __syncthreads();
        cur[r0][w0] = nw0;
        if ((w0 == 1 || w0 == 2) && r0 >= HALO && r0 < HALO + TILE) {
            uint32_t nb = nw0 & ~old0;
            while (nb) { int bit = __ffs(nb) - 1; nb &= nb - 1;
                         dtile[r0 - HALO][(w0 - 1) * 32 + bit] = (uint8_t)it; }
        }
        if (has1) {
            cur[r1][w1] = nw1;
            if ((w1 == 1 || w1 == 2) && r1 >= HALO && r1 < HALO + TILE) {
                uint32_t nb = nw1 & ~old1;
                while (nb) { int bit = __ffs(nb) - 1; nb &= nb - 1;
                             dtile[r1 - HALO][(w1 - 1) * 32 + bit] = (uint8_t)it; }
            }
        }
        __syncthreads();
    }

    // Phase B: CE over the 64x64 tile; 16 px/thread as 4 float4-quads
    float partial = 0.0f;
    const float* inb  = in  + (size_t)b * NC * HW;
    const int*   tgtb = tgt + (size_t)b * HW;
    #pragma unroll
    for (int g = 0; g < 4; g++) {
        int q = t + 256 * g;
        int row = q >> 4, quad = q & 15;
        int off = (ry + row) * IMG_W + tx * TILE + quad * 4;
        const float* base = inb + off;
        float v[NC][4];
        #pragma unroll
        for (int c = 0; c < NC; c++) {
            float4 f = *(const float4*)(base + (size_t)c * HW);
            v[c][0] = f.x; v[c][1] = f.y; v[c][2] = f.z; v[c][3] = f.w;
        }
        int4 t4 = *(const int4*)(tgtb + off);
        int tv[4] = {t4.x, t4.y, t4.z, t4.w};
        uint32_t d4 = *(const uint32_t*)&dtile[row][quad * 4];
        #pragma unroll
        for (int j = 0; j < 4; j++) {
            float mx = v[0][j];
            #pragma unroll
            for (int c = 1; c < NC; c++) mx = fmaxf(mx, v[c][j]);
            float s = 0.0f;
            #pragma unroll
            for (int c = 0; c < NC; c++) s += __expf(v[c][j] - mx);
            float lse = mx + __logf(s);
            int tc = tv[j];
            float lt = v[0][j];
            #pragma unroll
            for (int c = 1; c < NC; c++) lt = (tc == c) ? v[c][j] : lt;
            float ce = lse - lt;
            float d = (float)((d4 >> (8 * j)) & 0xffu);
            partial += __expf(d * -0.2f) * ce;
        }
    }
    #pragma unroll
    for (int off = 32; off > 0; off >>= 1) partial += __shfl_down(partial, off);
    __shared__ float wsums[4];
    int lane = t & 63;
    int wid = t >> 6;
    if (lane == 0) wsums[wid] = partial;
    __syncthreads();
    if (t == 0)
        partials[blockIdx.x] = wsums[0] + wsums[1] + wsums[2] + wsums[3];
}

// ---------------------------------------------------------------------------
// Kernel 3: deterministic tree-reduce of 1024 partials -> mean. One block.
// ---------------------------------------------------------------------------
__global__ __launch_bounds__(256) void reduce_kernel(const float* __restrict__ partials,
                                                     float* __restrict__ out) {
    double s = 0.0;
    #pragma unroll
    for (int i = 0; i < NBLK / 256; i++)
        s += (double)partials[threadIdx.x + 256 * i];
    #pragma unroll
    for (int off = 32; off > 0; off >>= 1) s += __shfl_down(s, off);
    __shared__ double wsums[4];
    int lane = threadIdx.x & 63;
    int wid = threadIdx.x >> 6;
    if (lane == 0) wsums[wid] = s;
    __syncthreads();
    if (threadIdx.x == 0) {
        double tot = wsums[0] + wsums[1] + wsums[2] + wsums[3];
        out[0] = (float)(tot * (1.0 / (double)((size_t)NB * HW)));
    }
}

extern "C" void kernel_launch(void* const* d_in, const int* in_sizes, int n_in,
                              void* d_out, int out_size, void* d_ws, size_t ws_size,
                              hipStream_t stream) {
    const float* in  = (const float*)d_in[0];
    const int*   tgt = (const int*)d_in[1];
    float* out = (float*)d_out;

    char* ws = (char*)d_ws;
    uint32_t* mask     = (uint32_t*)(ws + 256);                  // 512 KB
    float*    partials = (float*)(ws + 256 + (size_t)NB * (HW / 32) * 4); // 4 KB

    boundary_kernel<<<NB * IMG_H, IMG_W, 0, stream>>>(tgt, mask);
    distce_kernel<<<NBLK, 256, 0, stream>>>(in, tgt, mask, partials);
    reduce_kernel<<<1, 256, 0, stream>>>(partials, out);
}